// Round 2
// baseline (3093.762 us; speedup 1.0000x reference)
//
#include <hip/hip_runtime.h>
#include <math.h>

#define BB 32
#define CC 192
#define HEADS 6
#define WS 8
#define SSH 4
#define NN 64
#define NWIN 64
#define HD 32
#define HID 768
#define NTOK (BB * 64 * 64)   // 131072 tokens
#define SCALE 0.17677669529663687f

// ---------------------------------------------------------------------------
// K1: LN1 + cyclic shift (-4,-4) + window partition -> hw (B*NW, N, C)
// one wave (64 lanes) per destination token
// ---------------------------------------------------------------------------
__global__ __launch_bounds__(256) void ln1_shift_kernel(
    const float* __restrict__ x, const float* __restrict__ gamma,
    const float* __restrict__ beta, float* __restrict__ hw) {
  const int gid = blockIdx.x * blockDim.x + threadIdx.x;
  const int T = gid >> 6;
  const int lane = threadIdx.x & 63;
  if (T >= NTOK) return;
  const int g = T >> 6;   // global window id
  const int n = T & 63;   // token within window
  const int b = g >> 6;
  const int w = g & 63;
  const int wr = w >> 3, wc = w & 7;
  const int i = n >> 3, j = n & 7;
  const int sr = ((wr << 3) + i + SSH) & 63;  // source row in original image
  const int sc = ((wc << 3) + j + SSH) & 63;
  const float* xp = x + ((size_t)b * 4096 + sr * 64 + sc) * CC;
  const float v0 = xp[lane], v1 = xp[lane + 64], v2 = xp[lane + 128];
  float s = v0 + v1 + v2;
  float sq = v0 * v0 + v1 * v1 + v2 * v2;
#pragma unroll
  for (int off = 1; off < 64; off <<= 1) {
    s += __shfl_xor(s, off);
    sq += __shfl_xor(sq, off);
  }
  const float mean = s * (1.0f / 192.0f);
  const float var = sq * (1.0f / 192.0f) - mean * mean;
  const float rstd = rsqrtf(var + 1e-5f);
  float* op = hw + (size_t)T * CC;
  op[lane]       = (v0 - mean) * rstd * gamma[lane]       + beta[lane];
  op[lane + 64]  = (v1 - mean) * rstd * gamma[lane + 64]  + beta[lane + 64];
  op[lane + 128] = (v2 - mean) * rstd * gamma[lane + 128] + beta[lane + 128];
}

// ---------------------------------------------------------------------------
// K2: windowed attention. One block (256 thr) per window. For each head:
// qkv (64x32 each) from hw (global, broadcast loads) -> LDS; scores + bias +
// shift-mask -> softmax -> PV. Per-head output kept in registers; written
// in-place over hw at the very end (block owns its window).
// ---------------------------------------------------------------------------
__global__ __launch_bounds__(256) void attn_kernel(
    float* __restrict__ hw, const float* __restrict__ qkvw,
    const float* __restrict__ qkvb, const float* __restrict__ rpb) {
  __shared__ float qs[NN * 33];
  __shared__ float ks[NN * 33];
  __shared__ float vs[NN * 33];
  __shared__ float at[NN * 65];

  const int g = blockIdx.x;
  const int t = threadIdx.x;
  const int w = g & 63;
  const int wr = w >> 3, wc = w & 7;
  float* base = hw + (size_t)g * (NN * CC);

  const int c  = t & 31;   // head-dim col (qkv + PV phases)
  const int rg = t >> 5;   // 0..7 row group of 8 rows
  const int m  = t & 63;   // score column
  const int ng = t >> 6;   // 0..3 score row group of 16 rows

  // shift-mask region label for score-column token m
  const int i2 = m >> 3, j2 = m & 7;
  const int sr2 = (wr << 3) + i2, sc2 = (wc << 3) + j2;
  const int lab2 = (sr2 < 56 ? 0 : (sr2 < 60 ? 1 : 2)) * 3 +
                   (sc2 < 56 ? 0 : (sc2 < 60 ? 1 : 2));

  float oreg[48];
#pragma unroll
  for (int i = 0; i < 48; ++i) oreg[i] = 0.0f;

#pragma unroll
  for (int h = 0; h < HEADS; ++h) {
    // ---- qkv for this head: rows rg*8..+7, col c ----
    float aq[8], ak[8], av[8];
#pragma unroll
    for (int i = 0; i < 8; ++i) { aq[i] = 0.f; ak[i] = 0.f; av[i] = 0.f; }
    for (int ch = 0; ch < CC; ch += 4) {
      float wq[4], wk[4], wv[4];
#pragma unroll
      for (int cc = 0; cc < 4; ++cc) {
        const float* wp = qkvw + (size_t)(ch + cc) * 576 + h * 32 + c;
        wq[cc] = wp[0];
        wk[cc] = wp[192];
        wv[cc] = wp[384];
      }
#pragma unroll
      for (int i = 0; i < 8; ++i) {
        const int r = (rg << 3) + i;
        const float4 a = *(const float4*)(base + r * CC + ch);
        aq[i] = fmaf(a.x, wq[0], fmaf(a.y, wq[1], fmaf(a.z, wq[2], fmaf(a.w, wq[3], aq[i]))));
        ak[i] = fmaf(a.x, wk[0], fmaf(a.y, wk[1], fmaf(a.z, wk[2], fmaf(a.w, wk[3], ak[i]))));
        av[i] = fmaf(a.x, wv[0], fmaf(a.y, wv[1], fmaf(a.z, wv[2], fmaf(a.w, wv[3], av[i]))));
      }
    }
    {
      const float bq = qkvb[h * 32 + c];
      const float bk = qkvb[192 + h * 32 + c];
      const float bv = qkvb[384 + h * 32 + c];
#pragma unroll
      for (int i = 0; i < 8; ++i) {
        const int r = (rg << 3) + i;
        qs[r * 33 + c] = (aq[i] + bq) * SCALE;
        ks[r * 33 + c] = ak[i] + bk;
        vs[r * 33 + c] = av[i] + bv;
      }
    }
    __syncthreads();

    // ---- scores: rows ng*16..+15, column m ----
#pragma unroll
    for (int i = 0; i < 16; ++i) {
      const int n = (ng << 4) + i;
      const int i1 = n >> 3, j1 = n & 7;
      float acc = rpb[((i1 - i2 + 7) * 15 + (j1 - j2 + 7)) * HEADS + h];
      const int sr1 = (wr << 3) + i1, sc1 = (wc << 3) + j1;
      const int lab1 = (sr1 < 56 ? 0 : (sr1 < 60 ? 1 : 2)) * 3 +
                       (sc1 < 56 ? 0 : (sc1 < 60 ? 1 : 2));
      if (lab1 != lab2) acc -= 100.0f;
      const float* qrow = qs + n * 33;
      const float* krow = ks + m * 33;
#pragma unroll
      for (int d = 0; d < 32; ++d) acc = fmaf(qrow[d], krow[d], acc);
      at[n * 65 + m] = acc;
    }
    __syncthreads();

    // ---- softmax: one lane per row (wave 0) ----
    if (t < 64) {
      float* row = at + t * 65;
      float mx = row[0];
#pragma unroll
      for (int mm = 1; mm < 64; ++mm) mx = fmaxf(mx, row[mm]);
      float ssum = 0.f;
#pragma unroll
      for (int mm = 0; mm < 64; ++mm) {
        const float e = expf(row[mm] - mx);
        row[mm] = e;
        ssum += e;
      }
      const float inv = 1.0f / ssum;
#pragma unroll
      for (int mm = 0; mm < 64; ++mm) row[mm] *= inv;
    }
    __syncthreads();

    // ---- PV: rows rg*8..+7, col c ----
#pragma unroll
    for (int i = 0; i < 8; ++i) {
      const int n = (rg << 3) + i;
      const float* prow = at + n * 65;
      float acc = 0.f;
#pragma unroll 16
      for (int mm = 0; mm < 64; ++mm) acc = fmaf(prow[mm], vs[mm * 33 + c], acc);
      oreg[h * 8 + i] = acc;
    }
    __syncthreads();  // before next head overwrites qs/ks/vs/at
  }

  // ---- write o back in place over hw (all reads of hw are done) ----
#pragma unroll
  for (int i = 0; i < 8; ++i) {
    const int r = (rg << 3) + i;
#pragma unroll
    for (int h = 0; h < HEADS; ++h) {
      base[r * CC + h * 32 + c] = oreg[h * 8 + i];
    }
  }
}

// ---------------------------------------------------------------------------
// K3: proj GEMM (per-window 64x192 @ 192x192) + bias, then window-reverse +
// reverse shift scatter + residual add -> d_out = x2
// ---------------------------------------------------------------------------
__global__ __launch_bounds__(256) void proj_kernel(
    const float* __restrict__ hw, const float* __restrict__ pw,
    const float* __restrict__ pb, const float* __restrict__ x,
    float* __restrict__ out) {
  const int g = blockIdx.x;
  const int t = threadIdx.x;
  const int c = t & 63;
  const int rg = t >> 6;  // 0..3, rows rg*16..+15
  const float* base = hw + (size_t)g * (NN * CC);
  float acc[16][3];
#pragma unroll
  for (int i = 0; i < 16; ++i)
#pragma unroll
    for (int k = 0; k < 3; ++k) acc[i][k] = 0.f;

  for (int ch = 0; ch < CC; ch += 4) {
    float wv[4][3];
#pragma unroll
    for (int cc = 0; cc < 4; ++cc) {
      const float* wp = pw + (size_t)(ch + cc) * CC + c;
#pragma unroll
      for (int k = 0; k < 3; ++k) wv[cc][k] = wp[64 * k];
    }
#pragma unroll
    for (int i = 0; i < 16; ++i) {
      const int r = (rg << 4) + i;
      const float4 a = *(const float4*)(base + r * CC + ch);
#pragma unroll
      for (int k = 0; k < 3; ++k) {
        acc[i][k] = fmaf(a.x, wv[0][k],
                    fmaf(a.y, wv[1][k],
                    fmaf(a.z, wv[2][k],
                    fmaf(a.w, wv[3][k], acc[i][k]))));
      }
    }
  }
  const int b = g >> 6;
  const int w = g & 63;
  const int wr = w >> 3, wc = w & 7;
  float pbv[3];
#pragma unroll
  for (int k = 0; k < 3; ++k) pbv[k] = pb[c + 64 * k];
#pragma unroll
  for (int i = 0; i < 16; ++i) {
    const int n = (rg << 4) + i;
    const int dr = ((wr << 3) + (n >> 3) + SSH) & 63;
    const int dc = ((wc << 3) + (n & 7) + SSH) & 63;
    const size_t dst = ((size_t)b * 4096 + dr * 64 + dc) * CC;
#pragma unroll
    for (int k = 0; k < 3; ++k) {
      out[dst + c + 64 * k] = x[dst + c + 64 * k] + acc[i][k] + pbv[k];
    }
  }
}

// ---------------------------------------------------------------------------
// K4: fused LN2 + fc1 + exact GELU + fc2 + residual, 16 tokens per block.
// Hidden (16x768) lives in LDS. Reads x2 from d_out, writes final to d_out.
// ---------------------------------------------------------------------------
__global__ __launch_bounds__(256) void mlp_kernel(
    float* __restrict__ out, const float* __restrict__ g2,
    const float* __restrict__ b2, const float* __restrict__ w1,
    const float* __restrict__ b1, const float* __restrict__ w2,
    const float* __restrict__ bo) {
  __shared__ float xn[16 * CC];
  __shared__ float hid[16 * HID];
  const size_t T0 = (size_t)blockIdx.x * 16;
  const int t = threadIdx.x;

  // ---- LN2: 16 lanes per token ----
  {
    const int tok = t >> 4;
    const int l = t & 15;
    const float* xp = out + (T0 + tok) * CC;
    float v[12], s = 0.f, sq = 0.f;
#pragma unroll
    for (int k = 0; k < 12; ++k) {
      v[k] = xp[l + 16 * k];
      s += v[k];
      sq += v[k] * v[k];
    }
#pragma unroll
    for (int msk = 1; msk < 16; msk <<= 1) {
      s += __shfl_xor(s, msk);
      sq += __shfl_xor(sq, msk);
    }
    const float mean = s * (1.0f / 192.0f);
    const float var = sq * (1.0f / 192.0f) - mean * mean;
    const float rstd = rsqrtf(var + 1e-5f);
#pragma unroll
    for (int k = 0; k < 12; ++k) {
      const int ch = l + 16 * k;
      xn[tok * CC + ch] = (v[k] - mean) * rstd * g2[ch] + b2[ch];
    }
  }
  __syncthreads();

  // ---- fc1 + GELU: cols {t, t+256, t+512}, rows 0..15 ----
  {
    float a1[16][3];
#pragma unroll
    for (int r = 0; r < 16; ++r)
#pragma unroll
      for (int k = 0; k < 3; ++k) a1[r][k] = 0.f;
    for (int ch = 0; ch < CC; ch += 4) {
      float wv[4][3];
#pragma unroll
      for (int cc = 0; cc < 4; ++cc) {
        const float* wp = w1 + (size_t)(ch + cc) * HID + t;
#pragma unroll
        for (int k = 0; k < 3; ++k) wv[cc][k] = wp[256 * k];
      }
#pragma unroll
      for (int r = 0; r < 16; ++r) {
        const float4 a = *(const float4*)(xn + r * CC + ch);
#pragma unroll
        for (int k = 0; k < 3; ++k) {
          a1[r][k] = fmaf(a.x, wv[0][k],
                     fmaf(a.y, wv[1][k],
                     fmaf(a.z, wv[2][k],
                     fmaf(a.w, wv[3][k], a1[r][k]))));
        }
      }
    }
#pragma unroll
    for (int r = 0; r < 16; ++r) {
#pragma unroll
      for (int k = 0; k < 3; ++k) {
        const float hv = a1[r][k] + b1[t + 256 * k];
        hid[r * HID + t + 256 * k] =
            0.5f * hv * (1.0f + erff(hv * 0.70710678118654752f));
      }
    }
  }
  __syncthreads();

  // ---- fc2 + residual: cols {c, c+64, c+128}, rows rg*4..+3 ----
  {
    const int c = t & 63;
    const int rg = t >> 6;
    float a2[4][3];
#pragma unroll
    for (int i = 0; i < 4; ++i)
#pragma unroll
      for (int j = 0; j < 3; ++j) a2[i][j] = 0.f;
    for (int k = 0; k < HID; k += 4) {
      float wv[4][3];
#pragma unroll
      for (int kk = 0; kk < 4; ++kk) {
        const float* wp = w2 + (size_t)(k + kk) * CC + c;
#pragma unroll
        for (int j = 0; j < 3; ++j) wv[kk][j] = wp[64 * j];
      }
#pragma unroll
      for (int i = 0; i < 4; ++i) {
        const int r = (rg << 2) + i;
        const float4 hh = *(const float4*)(hid + r * HID + k);
#pragma unroll
        for (int j = 0; j < 3; ++j) {
          a2[i][j] = fmaf(hh.x, wv[0][j],
                     fmaf(hh.y, wv[1][j],
                     fmaf(hh.z, wv[2][j],
                     fmaf(hh.w, wv[3][j], a2[i][j]))));
        }
      }
    }
#pragma unroll
    for (int i = 0; i < 4; ++i) {
      const int r = (rg << 2) + i;
      float* op = out + (T0 + r) * CC;
#pragma unroll
      for (int j = 0; j < 3; ++j) {
        const int ch = c + 64 * j;
        op[ch] = op[ch] + a2[i][j] + bo[ch];
      }
    }
  }
}

// ---------------------------------------------------------------------------
extern "C" void kernel_launch(void* const* d_in, const int* in_sizes, int n_in,
                              void* d_out, int out_size, void* d_ws, size_t ws_size,
                              hipStream_t stream) {
  const float* x    = (const float*)d_in[0];
  const float* n1g  = (const float*)d_in[1];
  const float* n1b  = (const float*)d_in[2];
  const float* qkvw = (const float*)d_in[3];
  const float* qkvb = (const float*)d_in[4];
  const float* rpb  = (const float*)d_in[5];
  const float* pw   = (const float*)d_in[6];
  const float* pb   = (const float*)d_in[7];
  const float* n2g  = (const float*)d_in[8];
  const float* n2b  = (const float*)d_in[9];
  const float* w1   = (const float*)d_in[10];
  const float* b1   = (const float*)d_in[11];
  const float* w2   = (const float*)d_in[12];
  const float* b2   = (const float*)d_in[13];
  float* out = (float*)d_out;
  float* hw  = (float*)d_ws;  // 131072 * 192 floats = 100663296 bytes

  ln1_shift_kernel<<<NTOK / 4, 256, 0, stream>>>(x, n1g, n1b, hw);
  attn_kernel<<<BB * NWIN, 256, 0, stream>>>(hw, qkvw, qkvb, rpb);
  proj_kernel<<<BB * NWIN, 256, 0, stream>>>(hw, pw, pb, x, out);
  mlp_kernel<<<NTOK / 16, 256, 0, stream>>>(out, n2g, n2b, w1, b1, w2, b2);
}

// Round 4
// 955.479 us; speedup vs baseline: 3.2379x; 3.2379x over previous
//
#include <hip/hip_runtime.h>
#include <math.h>

typedef float f32x4 __attribute__((ext_vector_type(4)));
typedef short short8 __attribute__((ext_vector_type(8)));
typedef unsigned short u16;

#define BB 32
#define CC 192
#define HEADS 6
#define NN 64
#define HID 768
#define NTOK (BB * 64 * 64)
#define SCALE 0.17677669529663687f

#define MFMA(a, b, c) __builtin_amdgcn_mfma_f32_16x16x32_bf16(a, b, c, 0, 0, 0)

__device__ __forceinline__ u16 f2bf(float f) {
  union { float f; unsigned int u; } cv;
  cv.f = f;
  unsigned int u = cv.u;
  u += 0x7fffu + ((u >> 16) & 1u);
  return (u16)(u >> 16);
}

__device__ __forceinline__ f32x4 vzero() {
  f32x4 v;
  v[0] = 0.f; v[1] = 0.f; v[2] = 0.f; v[3] = 0.f;
  return v;
}

// A-style fragment read from swizzled LDS bf16 matrix (also used for B-frags of
// K^T and V^T which share the same per-lane pattern). pitch in elements.
__device__ __forceinline__ short8 ldsA(const u16* M, int pitch, int r0, int k0, int lane) {
  const int r = r0 + (lane & 15);
  const int cb = ((k0 + ((lane >> 4) << 3)) << 1) ^ ((r & 7) << 4);
  return *(const short8*)(M + r * pitch + (cb >> 1));
}

// B fragment from global K-contiguous (transposed) bf16 weight [N][K].
__device__ __forceinline__ short8 glbB(const u16* W, int pitch, int n0, int k0, int lane) {
  const int n = n0 + (lane & 15);
  return *(const short8*)(W + (size_t)n * pitch + k0 + ((lane >> 4) << 3));
}

// ---------------------------------------------------------------------------
// K0: convert + transpose weights to bf16 K-contiguous tables in ws
// ---------------------------------------------------------------------------
__global__ __launch_bounds__(256) void prep_kernel(
    const float* __restrict__ qkvw, const float* __restrict__ pw,
    const float* __restrict__ w1, const float* __restrict__ w2,
    u16* __restrict__ wqkvT, u16* __restrict__ projT,
    u16* __restrict__ w1T, u16* __restrict__ w2T) {
  const int id = blockIdx.x * 256 + threadIdx.x;
  if (id < 576 * 192) { const int n = id / 192, k = id - n * 192; wqkvT[id] = f2bf(qkvw[k * 576 + n]); }
  if (id < 192 * 192) { const int n = id / 192, k = id - n * 192; projT[id] = f2bf(pw[k * 192 + n]); }
  if (id < 768 * 192) { const int n = id / 192, k = id - n * 192; w1T[id] = f2bf(w1[k * 768 + n]); }
  if (id < 192 * 768) { const int n = id / 768, k = id - n * 768; w2T[id] = f2bf(w2[k * 192 + n]); }
}

// ---------------------------------------------------------------------------
// K1: LN1 + cyclic shift (-4,-4) + window partition -> hw bf16 (B*nW, 64, 192)
// ---------------------------------------------------------------------------
__global__ __launch_bounds__(256) void ln1_kernel(
    const float* __restrict__ x, const float* __restrict__ gamma,
    const float* __restrict__ beta, u16* __restrict__ hw) {
  const int gid = blockIdx.x * blockDim.x + threadIdx.x;
  const int T = gid >> 6;
  const int lane = threadIdx.x & 63;
  if (T >= NTOK) return;
  const int g = T >> 6;
  const int n = T & 63;
  const int b = g >> 6;
  const int w = g & 63;
  const int wr = w >> 3, wc = w & 7;
  const int sr = ((wr << 3) + (n >> 3) + 4) & 63;
  const int sc = ((wc << 3) + (n & 7) + 4) & 63;
  const float* xp = x + ((size_t)b * 4096 + sr * 64 + sc) * CC;
  const float v0 = xp[lane], v1 = xp[lane + 64], v2 = xp[lane + 128];
  float s = v0 + v1 + v2;
  float sq = v0 * v0 + v1 * v1 + v2 * v2;
#pragma unroll
  for (int off = 1; off < 64; off <<= 1) {
    s += __shfl_xor(s, off);
    sq += __shfl_xor(sq, off);
  }
  const float mean = s * (1.0f / 192.0f);
  const float var = sq * (1.0f / 192.0f) - mean * mean;
  const float rstd = rsqrtf(var + 1e-5f);
  u16* op = hw + (size_t)T * CC;
  op[lane]       = f2bf((v0 - mean) * rstd * gamma[lane]       + beta[lane]);
  op[lane + 64]  = f2bf((v1 - mean) * rstd * gamma[lane + 64]  + beta[lane + 64]);
  op[lane + 128] = f2bf((v2 - mean) * rstd * gamma[lane + 128] + beta[lane + 128]);
}

// ---------------------------------------------------------------------------
// K2: windowed attention, MFMA. 1 block = 1 window, 8 waves.
// ---------------------------------------------------------------------------
__global__ __launch_bounds__(512) void attn_kernel(
    u16* __restrict__ hw, const u16* __restrict__ wqkvT,
    const float* __restrict__ qkvb, const float* __restrict__ rpb) {
  __shared__ u16 Xs[64 * 192];
  __shared__ u16 Qs[64 * 192];
  __shared__ u16 Ks[64 * 192];
  __shared__ u16 Vt[192 * 64];     // [channel][token]
  __shared__ float Sb[2][64 * 68]; // padded pitch 68
  __shared__ u16 Pb[2][64 * 64];

  const int g = blockIdx.x;
  const int t = threadIdx.x;
  const int w = t >> 6;
  const int lane = t & 63;
  const int wr = (g >> 3) & 7, wc = g & 7;
  u16* win = hw + (size_t)g * (64 * 192);

  // stage window into Xs (swizzled), 16B units
#pragma unroll
  for (int u = 0; u < 3; ++u) {
    const int d = (t * 3 + u) << 4;
    const int row = d / 384;
    const int cb = d - row * 384;
    const short8 v = *(const short8*)((const char*)win + d);
    *(short8*)((char*)Xs + row * 384 + (cb ^ ((row & 7) << 4))) = v;
  }
  __syncthreads();

  // ---- QKV GEMM: 64x192 @ 192x576 ----
  const int ntbeg = (w < 4) ? w * 5 : 20 + (w - 4) * 4;
  const int ntcnt = (w < 4) ? 5 : 4;
  f32x4 acc[5][4];
#pragma unroll
  for (int p = 0; p < 5; ++p)
#pragma unroll
    for (int m = 0; m < 4; ++m) acc[p][m] = vzero();
#pragma unroll
  for (int kk = 0; kk < 6; ++kk) {
    const int k0 = kk << 5;
    short8 a[4];
#pragma unroll
    for (int m = 0; m < 4; ++m) a[m] = ldsA(Xs, 192, m << 4, k0, lane);
#pragma unroll
    for (int p = 0; p < 5; ++p) {
      int nt = ntbeg + p;
      if (nt > 35) nt = 35;  // waves 4-7 duplicate last tile (discarded)
      const short8 b = glbB(wqkvT, 192, nt << 4, k0, lane);
#pragma unroll
      for (int m = 0; m < 4; ++m) acc[p][m] = MFMA(a[m], b, acc[p][m]);
    }
  }
#pragma unroll
  for (int p = 0; p < 5; ++p) {
    if (p < ntcnt) {
      const int cg = ((ntbeg + p) << 4) + (lane & 15);
      const float bias = qkvb[cg];
#pragma unroll
      for (int m = 0; m < 4; ++m) {
#pragma unroll
        for (int i = 0; i < 4; ++i) {
          const int r = (m << 4) + ((lane >> 4) << 2) + i;
          const float val = acc[p][m][i] + bias;
          if (cg < 192) {
            const int cb = (cg << 1) ^ ((r & 7) << 4);
            Qs[r * 192 + (cb >> 1)] = f2bf(val * SCALE);
          } else if (cg < 384) {
            const int cb = ((cg - 192) << 1) ^ ((r & 7) << 4);
            Ks[r * 192 + (cb >> 1)] = f2bf(val);
          } else {
            const int vc = cg - 384;
            const int cb = (r << 1) ^ ((vc & 7) << 4);
            Vt[vc * 64 + (cb >> 1)] = f2bf(val);
          }
        }
      }
    }
  }
  __syncthreads();

  // ---- per-head: scores -> softmax -> PV. wave = (subgroup s, m-tile mt) ----
  const int s = w >> 2;
  const int mt = w & 3;
  float* S = Sb[s];
  u16* P = Pb[s];
  for (int hh = 0; hh < 3; ++hh) {
    const int h = s * 3 + hh;
    {
      const short8 aq = ldsA(Qs, 192, mt << 4, h << 5, lane);
      const int cbase = lane & 15;
#pragma unroll
      for (int kb = 0; kb < 4; ++kb) {
        const short8 bk = ldsA(Ks, 192, kb << 4, h << 5, lane);
        const f32x4 d = MFMA(aq, bk, vzero());
        const int c = (kb << 4) + cbase;
        const int i2 = c >> 3, j2 = c & 7;
        const int gr2 = (wr << 3) + i2, gc2 = (wc << 3) + j2;
        const int lab2 = (gr2 < 56 ? 0 : (gr2 < 60 ? 1 : 2)) * 3 +
                         (gc2 < 56 ? 0 : (gc2 < 60 ? 1 : 2));
#pragma unroll
        for (int i = 0; i < 4; ++i) {
          const int r = (mt << 4) + ((lane >> 4) << 2) + i;
          const int i1 = r >> 3, j1 = r & 7;
          const int gr1 = (wr << 3) + i1, gc1 = (wc << 3) + j1;
          const int lab1 = (gr1 < 56 ? 0 : (gr1 < 60 ? 1 : 2)) * 3 +
                           (gc1 < 56 ? 0 : (gc1 < 60 ? 1 : 2));
          float v = d[i] + rpb[((i1 - i2 + 7) * 15 + (j1 - j2 + 7)) * HEADS + h];
          if (lab1 != lab2) v -= 100.f;
          S[r * 68 + c] = v;
        }
      }
    }
    __syncthreads();
    {  // softmax: 4 lanes per row, 16 cols each
      const int r = (mt << 4) + (lane >> 2);
      const int c0 = (lane & 3) << 4;
      float v[16];
      float mx = -3.0e38f;
#pragma unroll
      for (int q = 0; q < 16; ++q) { v[q] = S[r * 68 + c0 + q]; mx = fmaxf(mx, v[q]); }
      mx = fmaxf(mx, __shfl_xor(mx, 1));
      mx = fmaxf(mx, __shfl_xor(mx, 2));
      float sum = 0.f;
#pragma unroll
      for (int q = 0; q < 16; ++q) { v[q] = __expf(v[q] - mx); sum += v[q]; }
      sum += __shfl_xor(sum, 1);
      sum += __shfl_xor(sum, 2);
      const float inv = 1.0f / sum;
#pragma unroll
      for (int q = 0; q < 16; ++q) {
        const int cb = ((c0 + q) << 1) ^ ((r & 7) << 4);
        P[r * 64 + (cb >> 1)] = f2bf(v[q] * inv);
      }
    }
    __syncthreads();
    // PV: O rows 16mt..+15, cols h*32 + nb*16
#pragma unroll
    for (int nb = 0; nb < 2; ++nb) {
      f32x4 o = vzero();
#pragma unroll
      for (int ks = 0; ks < 2; ++ks) {
        const short8 ap = ldsA(P, 64, mt << 4, ks << 5, lane);
        const short8 bv = ldsA(Vt, 64, (h << 5) + (nb << 4), ks << 5, lane);
        o = MFMA(ap, bv, o);
      }
      const int c = (h << 5) + (nb << 4) + (lane & 15);
#pragma unroll
      for (int i = 0; i < 4; ++i) {
        const int r = (mt << 4) + ((lane >> 4) << 2) + i;
        win[r * 192 + c] = f2bf(o[i]);
      }
    }
  }
}

// ---------------------------------------------------------------------------
// K3: proj GEMM + bias + reverse shift scatter + residual -> out (fp32)
// ---------------------------------------------------------------------------
__global__ __launch_bounds__(256) void proj_kernel(
    const u16* __restrict__ hw, const u16* __restrict__ projT,
    const float* __restrict__ pb, const float* __restrict__ x,
    float* __restrict__ out) {
  __shared__ u16 Os[64 * 192];
  const int g = blockIdx.x;
  const int t = threadIdx.x;
  const int w = t >> 6;
  const int lane = t & 63;
  const int b_ = g >> 6;
  const int wr = (g >> 3) & 7, wc = g & 7;
  const u16* win = hw + (size_t)g * (64 * 192);
#pragma unroll
  for (int u = 0; u < 6; ++u) {
    const int d = (t * 6 + u) << 4;
    const int row = d / 384;
    const int cb = d - row * 384;
    const short8 v = *(const short8*)((const char*)win + d);
    *(short8*)((char*)Os + row * 384 + (cb ^ ((row & 7) << 4))) = v;
  }
  __syncthreads();
#pragma unroll
  for (int gi = 0; gi < 2; ++gi) {
    f32x4 acc[6];
#pragma unroll
    for (int p = 0; p < 6; ++p) acc[p] = vzero();
#pragma unroll
    for (int kk = 0; kk < 6; ++kk) {
      const int k0 = kk << 5;
      const short8 a = ldsA(Os, 192, w << 4, k0, lane);
#pragma unroll
      for (int p = 0; p < 6; ++p) {
        const short8 b = glbB(projT, 192, (gi * 6 + p) << 4, k0, lane);
        acc[p] = MFMA(a, b, acc[p]);
      }
    }
#pragma unroll
    for (int p = 0; p < 6; ++p) {
      const int col = ((gi * 6 + p) << 4) + (lane & 15);
      const float bias = pb[col];
#pragma unroll
      for (int i = 0; i < 4; ++i) {
        const int r = (w << 4) + ((lane >> 4) << 2) + i;
        const int dr = ((wr << 3) + (r >> 3) + 4) & 63;
        const int dc = ((wc << 3) + (r & 7) + 4) & 63;
        const size_t dst = ((size_t)b_ * 4096 + dr * 64 + dc) * 192 + col;
        out[dst] = x[dst] + acc[p][i] + bias;
      }
    }
  }
}

// ---------------------------------------------------------------------------
// K4: LN2 + fc1 + GELU + fc2 + residual. 64 tokens/block, 8 waves, H in LDS.
// ---------------------------------------------------------------------------
__global__ __launch_bounds__(512) void mlp_kernel(
    float* __restrict__ out, const float* __restrict__ g2,
    const float* __restrict__ bn2, const u16* __restrict__ w1T,
    const float* __restrict__ b1, const u16* __restrict__ w2T,
    const float* __restrict__ bo) {
  __shared__ u16 Xn[64 * 192];
  __shared__ u16 Hs[64 * 768];
  const size_t T0 = (size_t)blockIdx.x * 64;
  const int t = threadIdx.x;
  const int w = t >> 6;
  const int lane = t & 63;

  {  // LN2: 8 lanes per token, 24 ch each
    const int tok = t >> 3;
    const int ch0 = (t & 7) * 24;
    const float* xp = out + (T0 + tok) * 192 + ch0;
    float v[24];
    float s = 0.f, sq = 0.f;
#pragma unroll
    for (int q = 0; q < 6; ++q) {
      const float4 f4 = *(const float4*)(xp + q * 4);
      v[q * 4 + 0] = f4.x; v[q * 4 + 1] = f4.y;
      v[q * 4 + 2] = f4.z; v[q * 4 + 3] = f4.w;
    }
#pragma unroll
    for (int q = 0; q < 24; ++q) { s += v[q]; sq += v[q] * v[q]; }
#pragma unroll
    for (int msk = 1; msk < 8; msk <<= 1) {
      s += __shfl_xor(s, msk);
      sq += __shfl_xor(sq, msk);
    }
    const float mean = s * (1.f / 192.f);
    const float var = sq * (1.f / 192.f) - mean * mean;
    const float rstd = rsqrtf(var + 1e-5f);
#pragma unroll
    for (int q = 0; q < 12; ++q) {
      const int ch = ch0 + q * 2;
      const float a0 = (v[q * 2] - mean) * rstd * g2[ch] + bn2[ch];
      const float a1 = (v[q * 2 + 1] - mean) * rstd * g2[ch + 1] + bn2[ch + 1];
      const unsigned int pk = (unsigned int)f2bf(a0) | ((unsigned int)f2bf(a1) << 16);
      const int cb = (ch << 1) ^ ((tok & 7) << 4);
      *(unsigned int*)&Xn[tok * 192 + (cb >> 1)] = pk;
    }
  }
  __syncthreads();

  const int mt = w & 3;
  const int half = w >> 2;
  // ---- fc1 + GELU ----
#pragma unroll
  for (int gi = 0; gi < 2; ++gi) {
    f32x4 acc[12];
#pragma unroll
    for (int p = 0; p < 12; ++p) acc[p] = vzero();
#pragma unroll
    for (int kk = 0; kk < 6; ++kk) {
      const int k0 = kk << 5;
      const short8 a = ldsA(Xn, 192, mt << 4, k0, lane);
#pragma unroll
      for (int p = 0; p < 12; ++p) {
        const int nt = half * 24 + gi * 12 + p;
        const short8 b = glbB(w1T, 192, nt << 4, k0, lane);
        acc[p] = MFMA(a, b, acc[p]);
      }
    }
#pragma unroll
    for (int p = 0; p < 12; ++p) {
      const int col = ((half * 24 + gi * 12 + p) << 4) + (lane & 15);
      const float bias = b1[col];
#pragma unroll
      for (int i = 0; i < 4; ++i) {
        const int r = (mt << 4) + ((lane >> 4) << 2) + i;
        const float hv = acc[p][i] + bias;
        const float ge = 0.5f * hv * (1.0f + erff(hv * 0.70710678118654752f));
        const int cb = (col << 1) ^ ((r & 7) << 4);
        Hs[r * 768 + (cb >> 1)] = f2bf(ge);
      }
    }
  }
  __syncthreads();

  // ---- fc2 + residual ----
  {
    f32x4 acc[6];
#pragma unroll
    for (int p = 0; p < 6; ++p) acc[p] = vzero();
    for (int kk = 0; kk < 24; ++kk) {
      const int k0 = kk << 5;
      const short8 a = ldsA(Hs, 768, mt << 4, k0, lane);
#pragma unroll
      for (int p = 0; p < 6; ++p) {
        const int nt = half * 6 + p;
        const short8 b = glbB(w2T, 768, nt << 4, k0, lane);
        acc[p] = MFMA(a, b, acc[p]);
      }
    }
#pragma unroll
    for (int p = 0; p < 6; ++p) {
      const int col = ((half * 6 + p) << 4) + (lane & 15);
      const float bias = bo[col];
#pragma unroll
      for (int i = 0; i < 4; ++i) {
        const int r = (mt << 4) + ((lane >> 4) << 2) + i;
        float* op = out + (T0 + r) * 192 + col;
        *op = *op + acc[p][i] + bias;
      }
    }
  }
}

// ---------------------------------------------------------------------------
extern "C" void kernel_launch(void* const* d_in, const int* in_sizes, int n_in,
                              void* d_out, int out_size, void* d_ws, size_t ws_size,
                              hipStream_t stream) {
  const float* x    = (const float*)d_in[0];
  const float* n1g  = (const float*)d_in[1];
  const float* n1b  = (const float*)d_in[2];
  const float* qkvw = (const float*)d_in[3];
  const float* qkvb = (const float*)d_in[4];
  const float* rpb  = (const float*)d_in[5];
  const float* pw   = (const float*)d_in[6];
  const float* pb   = (const float*)d_in[7];
  const float* n2g  = (const float*)d_in[8];
  const float* n2b  = (const float*)d_in[9];
  const float* w1   = (const float*)d_in[10];
  const float* b1   = (const float*)d_in[11];
  const float* w2   = (const float*)d_in[12];
  const float* b2   = (const float*)d_in[13];
  float* out = (float*)d_out;

  u16* hw    = (u16*)d_ws;                       // 131072*192 bf16 = 50.3 MB
  u16* wqkvT = hw + (size_t)131072 * 192;        // [576][192]
  u16* projT = wqkvT + 576 * 192;                // [192][192]
  u16* w1T   = projT + 192 * 192;                // [768][192]
  u16* w2T   = w1T + 768 * 192;                  // [192][768]

  prep_kernel<<<576, 256, 0, stream>>>(qkvw, pw, w1, w2, wqkvT, projT, w1T, w2T);
  ln1_kernel<<<32768, 256, 0, stream>>>(x, n1g, n1b, hw);
  attn_kernel<<<2048, 512, 0, stream>>>(hw, wqkvT, qkvb, rpb);
  proj_kernel<<<2048, 256, 0, stream>>>(hw, projT, pb, x, out);
  mlp_kernel<<<2048, 512, 0, stream>>>(out, n2g, n2b, w1T, b1, w2T, b2);
}